// Round 7
// baseline (201.348 us; speedup 1.0000x reference)
//
#include <hip/hip_runtime.h>
#include <stdint.h>
#include <stddef.h>

typedef __bf16 bf16;
typedef __attribute__((ext_vector_type(8))) __bf16 bf16x8;
typedef __attribute__((ext_vector_type(4))) __bf16 bf16x4;
typedef __attribute__((ext_vector_type(4))) float  f32x4;

// ---------------- geometry ----------------
// B = 262144. node: (B,19,4) f32, edge: (B,36,4) f32.
// compact first-4 nonzero rows of each -> x[32]; L1 32->256 relu; L2 256->128 relu;
// L3 128->34; log_softmax. Output (B,34) f32.
//
// Global weight image (bf16 fragment-linear, built by prep_kernel in d_ws):
//   frag = 1024B: lane l holds 16B = W[k0..k0+8)[n], n = nt*16+(l&15), k0 = kk*32+8*(l>>4).
//   layout: W1 @0 (16 frags), W2 @16K (64 frags), W3 @80K (12 frags, N padded to 48),
//           biases @92K (f32 b1[256] b2[128] b3[48]) = 1728B.
// LDS holds only W1+W3+biases (30.4KB) + 8 waves x 2KB = 46.8KB -> 2 blocks/CU
// -> 16 waves/CU (4/SIMD). W2 fragments read from global image (L2-hot, coalesced).
#define W2GOFF (16*1024)
#define W3GOFF (80*1024)
#define BGOFF  (92*1024)

#define W1LOFF 0
#define W3LOFF (16*1024)
#define BLOFF  (28*1024)
#define STAGEB (28*1024 + 1728)     // 30400 B staged to LDS
#define PERW   2048                 // per-wave: x tile 1KB + stage 1KB
#define LDSSZ  (STAGEB + 8*PERW)    // 46784 B

// swizzle for [16 rows][64B] bf16 tiles: XOR 16B-chunk index with (row>>1)&3
#define SWZ(s) ((((s)>>1)&3)<<4)

__global__ void prep_kernel(const float* __restrict__ W1, const float* __restrict__ b1,
                            const float* __restrict__ W2, const float* __restrict__ b2,
                            const float* __restrict__ W3, const float* __restrict__ b3,
                            char* __restrict__ img)
{
  int tid = blockIdx.x * 256 + threadIdx.x;
  if (tid < 92 * 64) {                       // 5888 weight chunks
    int fid = tid >> 6, l = tid & 63;
    int m = l & 15, gg = l >> 4;
    const float* W; int stride, n, k0;
    if (fid < 16)      { W = W1; stride = 256; n = fid * 16 + m;            k0 = gg * 8; }
    else if (fid < 80) { int f = fid - 16; W = W2; stride = 128; n = (f >> 3) * 16 + m; k0 = (f & 7) * 32 + gg * 8; }
    else               { int f = fid - 80; W = W3; stride = 34;  n = (f >> 2) * 16 + m; k0 = (f & 3) * 32 + gg * 8; }
    bf16x8 v;
    #pragma unroll
    for (int j = 0; j < 8; ++j) {
      float x = (stride == 34 && n >= 34) ? 0.f : W[(size_t)(k0 + j) * stride + n];
      v[j] = (bf16)x;
    }
    *(bf16x8*)(img + (size_t)tid * 16) = v;
  } else if (tid < 92 * 64 + 432) {          // biases, flat f32
    int i = tid - 92 * 64;
    float v;
    if (i < 256)      v = b1[i];
    else if (i < 384) v = b2[i - 256];
    else              { int j = i - 384; v = (j < 34) ? b3[j] : 0.f; }
    ((float*)(img + BGOFF))[i] = v;
  }
}

// (512,2) is the ONLY annotation with proven non-spilling codegen (R1: 108 VGPR).
// (512,4) and all 1024-thread shapes clamp to 64 VGPR + spill (R2-R5).
// With 46.8KB LDS and ~110 VGPR, hardware co-schedules 2 blocks/CU = 16 waves.
__global__ __launch_bounds__(512, 2) void mlp_kernel(
    const float* __restrict__ node, const float* __restrict__ edge,
    const char* __restrict__ img, float* __restrict__ out)
{
  __shared__ __align__(16) char sm[LDSSZ];
  const int tid  = threadIdx.x;
  const int lane = tid & 63;
  const int w    = tid >> 6;                 // 0..7
  const int blk  = blockIdx.x;

  // stage W1 + W3 + biases to LDS (coalesced 16B copies), one barrier total
  for (int c = tid; c < STAGEB / 16; c += 512) {
    const char* src;
    if (c < 1024)      src = img + (size_t)c * 16;                    // W1
    else if (c < 1792) src = img + W3GOFF + (size_t)(c - 1024) * 16;  // W3
    else               src = img + BGOFF  + (size_t)(c - 1792) * 16;  // biases
    *(f32x4*)(sm + (size_t)c * 16) = *(const f32x4*)src;
  }
  __syncthreads();

  char* const xw  = sm + STAGEB + w * PERW;  // x tile (1KB, wave-private)
  char* const stg = xw + 1024;               // inter-layer stage (1KB)
  const float* const b1p = (const float*)(sm + BLOFF);
  const float* const b2p = b1p + 256;
  const float* const b3p = b1p + 384;
  const char* const w2l  = img + W2GOFF + (size_t)lane * 16;  // W2 global, lane-offset

  const int g   = lane >> 4;   // mfma 16-lane group
  const int m16 = lane & 15;   // sample col (compute) / weight row
  const int cl  = lane & 3;    // compaction lane within sample
  const int sl  = lane >> 2;   // compaction sample-in-tile (0..15)

  const float4* const np = (const float4*)node;   // 19 float4 per sample
  const float4* const ep = (const float4*)edge;   // 36 float4 per sample
  const f32x4 zf = {0.f, 0.f, 0.f, 0.f};

  #pragma unroll 1
  for (int p = 0; p < 4; ++p) {
    const int S = blk * 512 + p * 128 + w * 16;

    // ---- load raw rows (14 independent loads in flight), compact into xw ----
    {
      const int s = S + sl;
      float4 nf[5], ef[9];
      #pragma unroll
      for (int i = 0; i < 5; ++i) {
        const int r = cl + 4 * i;
        nf[i] = (r < 19) ? np[(size_t)s * 19 + r] : make_float4(0.f, 0.f, 0.f, 0.f);
      }
      #pragma unroll
      for (int i = 0; i < 9; ++i)
        ef[i] = ep[(size_t)s * 36 + cl + 4 * i];

      uint32_t nm = 0; unsigned long long em = 0;
      #pragma unroll
      for (int i = 0; i < 5; ++i) {
        const int r = cl + 4 * i;
        if (r < 19 && (nf[i].x != 0.f || nf[i].y != 0.f || nf[i].z != 0.f || nf[i].w != 0.f))
          nm |= (1u << r);
      }
      #pragma unroll
      for (int i = 0; i < 9; ++i) {
        const int r = cl + 4 * i;
        if (ef[i].x != 0.f || ef[i].y != 0.f || ef[i].z != 0.f || ef[i].w != 0.f)
          em |= (1ull << r);
      }
      nm |= __shfl_xor(nm, 1); nm |= __shfl_xor(nm, 2);
      em |= __shfl_xor(em, 1); em |= __shfl_xor(em, 2);
      // zero-init my two 8B slots of the row (8 slots covered by 4 lanes);
      // wave-lockstep: zeros land before data writes below.
      bf16x4 zb; zb[0] = (bf16)0.f; zb[1] = (bf16)0.f; zb[2] = (bf16)0.f; zb[3] = (bf16)0.f;
      *(bf16x4*)(xw + sl * 64 + ((8 * cl)      ^ SWZ(sl))) = zb;
      *(bf16x4*)(xw + sl * 64 + ((8 * cl + 32) ^ SWZ(sl))) = zb;
      #pragma unroll
      for (int i = 0; i < 5; ++i) {
        const int r = cl + 4 * i;
        if (r < 19 && ((nm >> r) & 1u)) {
          const int slot = __popc(nm & ((1u << r) - 1u));
          if (slot < 4) {
            bf16x4 pk; pk[0] = (bf16)nf[i].x; pk[1] = (bf16)nf[i].y; pk[2] = (bf16)nf[i].z; pk[3] = (bf16)nf[i].w;
            *(bf16x4*)(xw + sl * 64 + ((8 * slot) ^ SWZ(sl))) = pk;
          }
        }
      }
      #pragma unroll
      for (int i = 0; i < 9; ++i) {
        const int r = cl + 4 * i;
        if ((em >> r) & 1ull) {
          const int slot = __popcll(em & ((1ull << r) - 1ull));
          if (slot < 4) {
            bf16x4 pk; pk[0] = (bf16)ef[i].x; pk[1] = (bf16)ef[i].y; pk[2] = (bf16)ef[i].z; pk[3] = (bf16)ef[i].w;
            *(bf16x4*)(xw + sl * 64 + ((32 + 8 * slot) ^ SWZ(sl))) = pk;
          }
        }
      }
    }

    // x B-fragment: lane holds x[s=m16][8g .. 8g+8)
    bf16x8 xf = *(const bf16x8*)(xw + m16 * 64 + ((16 * g) ^ SWZ(m16)));

    // ---- L1 (32->256) fused into L2 (256->128) per 32-feature chunk ----
    f32x4 acc2[8];
    #pragma unroll
    for (int i = 0; i < 8; ++i) acc2[i] = zf;

    #pragma unroll
    for (int kk = 0; kk < 8; ++kk) {
      // issue this kk's 8 W2 fragment loads (global, L2-hot) early;
      // latency hides under the L1 stage below + 3 peer waves/SIMD.
      bf16x8 w2f[8];
      #pragma unroll
      for (int j = 0; j < 8; ++j)
        w2f[j] = *(const bf16x8*)(w2l + (size_t)(j * 8 + kk) * 1024);

      #pragma unroll
      for (int t = 0; t < 2; ++t) {
        const int nt1 = kk * 2 + t;
        bf16x8 wf = *(const bf16x8*)(sm + W1LOFF + nt1 * 1024 + lane * 16);
        f32x4 d = __builtin_amdgcn_mfma_f32_16x16x32_bf16(wf, xf, zf, 0, 0, 0);
        f32x4 b = *(const f32x4*)(b1p + nt1 * 16 + 4 * g);
        bf16x4 pk;
        #pragma unroll
        for (int r = 0; r < 4; ++r) pk[r] = (bf16)fmaxf(d[r] + b[r], 0.f);
        // D is [feature][sample]: lane has 4 consecutive features of sample m16
        *(bf16x4*)(stg + m16 * 64 + ((32 * t + 8 * g) ^ SWZ(m16))) = pk;
      }
      bf16x8 sf = *(const bf16x8*)(stg + m16 * 64 + ((16 * g) ^ SWZ(m16)));
      #pragma unroll
      for (int nt2 = 0; nt2 < 8; ++nt2)
        acc2[nt2] = __builtin_amdgcn_mfma_f32_16x16x32_bf16(w2f[nt2], sf, acc2[nt2], 0, 0, 0);
    }

    // ---- L2 out -> L3 (128->48 padded) ----
    f32x4 acc3[3];
    #pragma unroll
    for (int i = 0; i < 3; ++i) acc3[i] = zf;

    #pragma unroll
    for (int k2 = 0; k2 < 4; ++k2) {
      #pragma unroll
      for (int t = 0; t < 2; ++t) {
        const int nt2 = k2 * 2 + t;
        f32x4 b = *(const f32x4*)(b2p + nt2 * 16 + 4 * g);
        bf16x4 pk;
        #pragma unroll
        for (int r = 0; r < 4; ++r) pk[r] = (bf16)fmaxf(acc2[nt2][r] + b[r], 0.f);
        *(bf16x4*)(stg + m16 * 64 + ((32 * t + 8 * g) ^ SWZ(m16))) = pk;
      }
      bf16x8 sf = *(const bf16x8*)(stg + m16 * 64 + ((16 * g) ^ SWZ(m16)));
      #pragma unroll
      for (int nt3 = 0; nt3 < 3; ++nt3) {
        bf16x8 wf = *(const bf16x8*)(sm + W3LOFF + (nt3 * 4 + k2) * 1024 + lane * 16);
        acc3[nt3] = __builtin_amdgcn_mfma_f32_16x16x32_bf16(wf, sf, acc3[nt3], 0, 0, 0);
      }
    }

    // ---- log_softmax over 34 classes (features spread over 4 lane-groups) ----
    float z[12];
    #pragma unroll
    for (int nt3 = 0; nt3 < 3; ++nt3) {
      f32x4 b = *(const f32x4*)(b3p + nt3 * 16 + 4 * g);
      #pragma unroll
      for (int r = 0; r < 4; ++r) {
        const int f = nt3 * 16 + 4 * g + r;
        z[nt3 * 4 + r] = (f < 34) ? (acc3[nt3][r] + b[r]) : -1e30f;
      }
    }
    float mx = z[0];
    #pragma unroll
    for (int i = 1; i < 12; ++i) mx = fmaxf(mx, z[i]);
    mx = fmaxf(mx, __shfl_xor(mx, 16));
    mx = fmaxf(mx, __shfl_xor(mx, 32));
    float sum = 0.f;
    #pragma unroll
    for (int i = 0; i < 12; ++i) sum += __expf(z[i] - mx);
    sum += __shfl_xor(sum, 16);
    sum += __shfl_xor(sum, 32);
    const float lse = mx + __logf(sum);

    float* orow = out + (size_t)(S + m16) * 34;
    *(float2*)(orow +  0 + 4 * g) = make_float2(z[0] - lse, z[1] - lse);
    *(float2*)(orow +  2 + 4 * g) = make_float2(z[2] - lse, z[3] - lse);
    *(float2*)(orow + 16 + 4 * g) = make_float2(z[4] - lse, z[5] - lse);
    *(float2*)(orow + 18 + 4 * g) = make_float2(z[6] - lse, z[7] - lse);
    if (g == 0)
      *(float2*)(orow + 32) = make_float2(z[8] - lse, z[9] - lse);
  }
}

extern "C" void kernel_launch(void* const* d_in, const int* in_sizes, int n_in,
                              void* d_out, int out_size, void* d_ws, size_t ws_size,
                              hipStream_t stream)
{
  const float* node = (const float*)d_in[0];
  const float* edge = (const float*)d_in[1];
  const float* W1   = (const float*)d_in[2];
  const float* b1   = (const float*)d_in[3];
  const float* W2   = (const float*)d_in[4];
  const float* b2   = (const float*)d_in[5];
  const float* W3   = (const float*)d_in[6];
  const float* b3   = (const float*)d_in[7];
  char* img = (char*)d_ws;

  prep_kernel<<<25, 256, 0, stream>>>(W1, b1, W2, b2, W3, b3, img);
  mlp_kernel<<<512, 512, 0, stream>>>(node, edge, img, (float*)d_out);
}

// Round 8
// 103.548 us; speedup vs baseline: 1.9445x; 1.9445x over previous
//
#include <hip/hip_runtime.h>
#include <stdint.h>
#include <stddef.h>

typedef __bf16 bf16;
typedef __attribute__((ext_vector_type(8))) __bf16 bf16x8;
typedef __attribute__((ext_vector_type(4))) __bf16 bf16x4;
typedef __attribute__((ext_vector_type(4))) float  f32x4;

// ---------------- geometry ----------------
// B = 262144. node: (B,19,4) f32, edge: (B,36,4) f32.
// compact first-4 nonzero rows of each -> x[32]; L1 32->256 relu; L2 256->128 relu;
// L3 128->34; log_softmax. Output (B,34) f32.
//
// Global weight image (bf16 fragment-linear, built by prep_kernel in d_ws):
//   frag = 1024B: lane l holds 16B = W[k0..k0+8)[n], n = nt*16+(l&15), k0 = kk*32+8*(l>>4).
//   layout: W1 @0 (16 frags), W2 @16K (64 frags), W3 @80K (12 frags, N padded to 48),
//           biases @92K (f32 b1[256] b2[128] b3[48]) = 1728B.
// LDS holds only W1+W3+biases (30.4KB) + 8 waves x 2KB = 46.8KB -> 2 blocks/CU
// -> 16 waves/CU (4/SIMD). W2 fragments read from global image (L2-hot, coalesced).
#define W2GOFF (16*1024)
#define W3GOFF (80*1024)
#define BGOFF  (92*1024)

#define W1LOFF 0
#define W3LOFF (16*1024)
#define BLOFF  (28*1024)
#define STAGEB (28*1024 + 1728)     // 30400 B staged to LDS
#define PERW   2048                 // per-wave: x tile 1KB + stage 1KB
#define LDSSZ  (STAGEB + 8*PERW)    // 46784 B

// swizzle for [16 rows][64B] bf16 tiles: XOR 16B-chunk index with (row>>1)&3
#define SWZ(s) ((((s)>>1)&3)<<4)

__global__ void prep_kernel(const float* __restrict__ W1, const float* __restrict__ b1,
                            const float* __restrict__ W2, const float* __restrict__ b2,
                            const float* __restrict__ W3, const float* __restrict__ b3,
                            char* __restrict__ img)
{
  int tid = blockIdx.x * 256 + threadIdx.x;
  if (tid < 92 * 64) {                       // 5888 weight chunks
    int fid = tid >> 6, l = tid & 63;
    int m = l & 15, gg = l >> 4;
    const float* W; int stride, n, k0;
    if (fid < 16)      { W = W1; stride = 256; n = fid * 16 + m;            k0 = gg * 8; }
    else if (fid < 80) { int f = fid - 16; W = W2; stride = 128; n = (f >> 3) * 16 + m; k0 = (f & 7) * 32 + gg * 8; }
    else               { int f = fid - 80; W = W3; stride = 34;  n = (f >> 2) * 16 + m; k0 = (f & 3) * 32 + gg * 8; }
    bf16x8 v;
    #pragma unroll
    for (int j = 0; j < 8; ++j) {
      float x = (stride == 34 && n >= 34) ? 0.f : W[(size_t)(k0 + j) * stride + n];
      v[j] = (bf16)x;
    }
    *(bf16x8*)(img + (size_t)tid * 16) = v;
  } else if (tid < 92 * 64 + 432) {          // biases, flat f32
    int i = tid - 92 * 64;
    float v;
    if (i < 256)      v = b1[i];
    else if (i < 384) v = b2[i - 256];
    else              { int j = i - 384; v = (j < 34) ? b3[j] : 0.f; }
    ((float*)(img + BGOFF))[i] = v;
  }
}

// (512,2): the only annotation with proven non-spilling codegen (R1: 108 VGPR).
// R7 spilled because the fully-unrolled kk loop exposed 64 hoistable global
// loads; here the kk loop stays rolled (unroll 1 + sched_barrier) so at most
// 8 W2 frags (32 VGPR) are in flight.
__global__ __launch_bounds__(512, 2) void mlp_kernel(
    const float* __restrict__ node, const float* __restrict__ edge,
    const char* __restrict__ img, float* __restrict__ out)
{
  __shared__ __align__(16) char sm[LDSSZ];
  const int tid  = threadIdx.x;
  const int lane = tid & 63;
  const int w    = tid >> 6;                 // 0..7
  const int blk  = blockIdx.x;

  // stage W1 + W3 + biases to LDS (coalesced 16B copies), one barrier total
  for (int c = tid; c < STAGEB / 16; c += 512) {
    const char* src;
    if (c < 1024)      src = img + (size_t)c * 16;                    // W1
    else if (c < 1792) src = img + W3GOFF + (size_t)(c - 1024) * 16;  // W3
    else               src = img + BGOFF  + (size_t)(c - 1792) * 16;  // biases
    *(f32x4*)(sm + (size_t)c * 16) = *(const f32x4*)src;
  }
  __syncthreads();

  char* const xw  = sm + STAGEB + w * PERW;  // x tile (1KB, wave-private)
  char* const stg = xw + 1024;               // inter-layer stage (1KB)
  const float* const b1p = (const float*)(sm + BLOFF);
  const float* const b2p = b1p + 256;
  const float* const b3p = b1p + 384;
  const char* const w2l  = img + W2GOFF + (size_t)lane * 16;  // W2 global, lane-offset

  const int g   = lane >> 4;   // mfma 16-lane group
  const int m16 = lane & 15;   // sample col (compute) / weight row
  const int cl  = lane & 3;    // compaction lane within sample
  const int sl  = lane >> 2;   // compaction sample-in-tile (0..15)

  const float4* const np = (const float4*)node;   // 19 float4 per sample
  const float4* const ep = (const float4*)edge;   // 36 float4 per sample
  const f32x4 zf = {0.f, 0.f, 0.f, 0.f};

  #pragma unroll 1
  for (int p = 0; p < 4; ++p) {
    const int S = blk * 512 + p * 128 + w * 16;

    // ---- load raw rows (14 independent loads in flight), compact into xw ----
    {
      const int s = S + sl;
      float4 nf[5], ef[9];
      #pragma unroll
      for (int i = 0; i < 5; ++i) {
        const int r = cl + 4 * i;
        nf[i] = (r < 19) ? np[(size_t)s * 19 + r] : make_float4(0.f, 0.f, 0.f, 0.f);
      }
      #pragma unroll
      for (int i = 0; i < 9; ++i)
        ef[i] = ep[(size_t)s * 36 + cl + 4 * i];

      uint32_t nm = 0; unsigned long long em = 0;
      #pragma unroll
      for (int i = 0; i < 5; ++i) {
        const int r = cl + 4 * i;
        if (r < 19 && (nf[i].x != 0.f || nf[i].y != 0.f || nf[i].z != 0.f || nf[i].w != 0.f))
          nm |= (1u << r);
      }
      #pragma unroll
      for (int i = 0; i < 9; ++i) {
        const int r = cl + 4 * i;
        if (ef[i].x != 0.f || ef[i].y != 0.f || ef[i].z != 0.f || ef[i].w != 0.f)
          em |= (1ull << r);
      }
      nm |= __shfl_xor(nm, 1); nm |= __shfl_xor(nm, 2);
      em |= __shfl_xor(em, 1); em |= __shfl_xor(em, 2);
      // zero-init my two 8B slots of the row (8 slots covered by 4 lanes);
      // wave-lockstep: zeros land before data writes below.
      bf16x4 zb; zb[0] = (bf16)0.f; zb[1] = (bf16)0.f; zb[2] = (bf16)0.f; zb[3] = (bf16)0.f;
      *(bf16x4*)(xw + sl * 64 + ((8 * cl)      ^ SWZ(sl))) = zb;
      *(bf16x4*)(xw + sl * 64 + ((8 * cl + 32) ^ SWZ(sl))) = zb;
      #pragma unroll
      for (int i = 0; i < 5; ++i) {
        const int r = cl + 4 * i;
        if (r < 19 && ((nm >> r) & 1u)) {
          const int slot = __popc(nm & ((1u << r) - 1u));
          if (slot < 4) {
            bf16x4 pk; pk[0] = (bf16)nf[i].x; pk[1] = (bf16)nf[i].y; pk[2] = (bf16)nf[i].z; pk[3] = (bf16)nf[i].w;
            *(bf16x4*)(xw + sl * 64 + ((8 * slot) ^ SWZ(sl))) = pk;
          }
        }
      }
      #pragma unroll
      for (int i = 0; i < 9; ++i) {
        const int r = cl + 4 * i;
        if ((em >> r) & 1ull) {
          const int slot = __popcll(em & ((1ull << r) - 1ull));
          if (slot < 4) {
            bf16x4 pk; pk[0] = (bf16)ef[i].x; pk[1] = (bf16)ef[i].y; pk[2] = (bf16)ef[i].z; pk[3] = (bf16)ef[i].w;
            *(bf16x4*)(xw + sl * 64 + ((32 + 8 * slot) ^ SWZ(sl))) = pk;
          }
        }
      }
    }

    // x B-fragment: lane holds x[s=m16][8g .. 8g+8)
    bf16x8 xf = *(const bf16x8*)(xw + m16 * 64 + ((16 * g) ^ SWZ(m16)));

    // ---- L1 (32->256) fused into L2 (256->128) per 32-feature chunk ----
    f32x4 acc2[8];
    #pragma unroll
    for (int i = 0; i < 8; ++i) acc2[i] = zf;

    #pragma unroll 1
    for (int kk = 0; kk < 8; ++kk) {
      __builtin_amdgcn_sched_barrier(0);     // no cross-iteration hoisting
      // first 4 W2 frags in flight; latency hidden by the L1 stage below
      bf16x8 w2a = *(const bf16x8*)(w2l + (size_t)(0 * 8 + kk) * 1024);
      bf16x8 w2b = *(const bf16x8*)(w2l + (size_t)(1 * 8 + kk) * 1024);
      bf16x8 w2c = *(const bf16x8*)(w2l + (size_t)(2 * 8 + kk) * 1024);
      bf16x8 w2d = *(const bf16x8*)(w2l + (size_t)(3 * 8 + kk) * 1024);

      #pragma unroll
      for (int t = 0; t < 2; ++t) {
        const int nt1 = kk * 2 + t;
        bf16x8 wf = *(const bf16x8*)(sm + W1LOFF + nt1 * 1024 + lane * 16);
        f32x4 d = __builtin_amdgcn_mfma_f32_16x16x32_bf16(wf, xf, zf, 0, 0, 0);
        f32x4 b = *(const f32x4*)(b1p + nt1 * 16 + 4 * g);
        bf16x4 pk;
        #pragma unroll
        for (int r = 0; r < 4; ++r) pk[r] = (bf16)fmaxf(d[r] + b[r], 0.f);
        // D is [feature][sample]: lane has 4 consecutive features of sample m16
        *(bf16x4*)(stg + m16 * 64 + ((32 * t + 8 * g) ^ SWZ(m16))) = pk;
      }
      bf16x8 sf = *(const bf16x8*)(stg + m16 * 64 + ((16 * g) ^ SWZ(m16)));

      // second 4 frags in flight; latency hidden by the 4 MFMAs below
      bf16x8 w2e = *(const bf16x8*)(w2l + (size_t)(4 * 8 + kk) * 1024);
      bf16x8 w2f = *(const bf16x8*)(w2l + (size_t)(5 * 8 + kk) * 1024);
      bf16x8 w2g = *(const bf16x8*)(w2l + (size_t)(6 * 8 + kk) * 1024);
      bf16x8 w2h = *(const bf16x8*)(w2l + (size_t)(7 * 8 + kk) * 1024);

      acc2[0] = __builtin_amdgcn_mfma_f32_16x16x32_bf16(w2a, sf, acc2[0], 0, 0, 0);
      acc2[1] = __builtin_amdgcn_mfma_f32_16x16x32_bf16(w2b, sf, acc2[1], 0, 0, 0);
      acc2[2] = __builtin_amdgcn_mfma_f32_16x16x32_bf16(w2c, sf, acc2[2], 0, 0, 0);
      acc2[3] = __builtin_amdgcn_mfma_f32_16x16x32_bf16(w2d, sf, acc2[3], 0, 0, 0);
      acc2[4] = __builtin_amdgcn_mfma_f32_16x16x32_bf16(w2e, sf, acc2[4], 0, 0, 0);
      acc2[5] = __builtin_amdgcn_mfma_f32_16x16x32_bf16(w2f, sf, acc2[5], 0, 0, 0);
      acc2[6] = __builtin_amdgcn_mfma_f32_16x16x32_bf16(w2g, sf, acc2[6], 0, 0, 0);
      acc2[7] = __builtin_amdgcn_mfma_f32_16x16x32_bf16(w2h, sf, acc2[7], 0, 0, 0);
    }

    // ---- L2 out -> L3 (128->48 padded) ----
    f32x4 acc3[3];
    #pragma unroll
    for (int i = 0; i < 3; ++i) acc3[i] = zf;

    #pragma unroll
    for (int k2 = 0; k2 < 4; ++k2) {
      #pragma unroll
      for (int t = 0; t < 2; ++t) {
        const int nt2 = k2 * 2 + t;
        f32x4 b = *(const f32x4*)(b2p + nt2 * 16 + 4 * g);
        bf16x4 pk;
        #pragma unroll
        for (int r = 0; r < 4; ++r) pk[r] = (bf16)fmaxf(acc2[nt2][r] + b[r], 0.f);
        *(bf16x4*)(stg + m16 * 64 + ((32 * t + 8 * g) ^ SWZ(m16))) = pk;
      }
      bf16x8 sf = *(const bf16x8*)(stg + m16 * 64 + ((16 * g) ^ SWZ(m16)));
      #pragma unroll
      for (int nt3 = 0; nt3 < 3; ++nt3) {
        bf16x8 wf = *(const bf16x8*)(sm + W3LOFF + (nt3 * 4 + k2) * 1024 + lane * 16);
        acc3[nt3] = __builtin_amdgcn_mfma_f32_16x16x32_bf16(wf, sf, acc3[nt3], 0, 0, 0);
      }
    }

    // ---- log_softmax over 34 classes (features spread over 4 lane-groups) ----
    float z[12];
    #pragma unroll
    for (int nt3 = 0; nt3 < 3; ++nt3) {
      f32x4 b = *(const f32x4*)(b3p + nt3 * 16 + 4 * g);
      #pragma unroll
      for (int r = 0; r < 4; ++r) {
        const int f = nt3 * 16 + 4 * g + r;
        z[nt3 * 4 + r] = (f < 34) ? (acc3[nt3][r] + b[r]) : -1e30f;
      }
    }
    float mx = z[0];
    #pragma unroll
    for (int i = 1; i < 12; ++i) mx = fmaxf(mx, z[i]);
    mx = fmaxf(mx, __shfl_xor(mx, 16));
    mx = fmaxf(mx, __shfl_xor(mx, 32));
    float sum = 0.f;
    #pragma unroll
    for (int i = 0; i < 12; ++i) sum += __expf(z[i] - mx);
    sum += __shfl_xor(sum, 16);
    sum += __shfl_xor(sum, 32);
    const float lse = mx + __logf(sum);

    float* orow = out + (size_t)(S + m16) * 34;
    *(float2*)(orow +  0 + 4 * g) = make_float2(z[0] - lse, z[1] - lse);
    *(float2*)(orow +  2 + 4 * g) = make_float2(z[2] - lse, z[3] - lse);
    *(float2*)(orow + 16 + 4 * g) = make_float2(z[4] - lse, z[5] - lse);
    *(float2*)(orow + 18 + 4 * g) = make_float2(z[6] - lse, z[7] - lse);
    if (g == 0)
      *(float2*)(orow + 32) = make_float2(z[8] - lse, z[9] - lse);
  }
}

extern "C" void kernel_launch(void* const* d_in, const int* in_sizes, int n_in,
                              void* d_out, int out_size, void* d_ws, size_t ws_size,
                              hipStream_t stream)
{
  const float* node = (const float*)d_in[0];
  const float* edge = (const float*)d_in[1];
  const float* W1   = (const float*)d_in[2];
  const float* b1   = (const float*)d_in[3];
  const float* W2   = (const float*)d_in[4];
  const float* b2   = (const float*)d_in[5];
  const float* W3   = (const float*)d_in[6];
  const float* b3   = (const float*)d_in[7];
  char* img = (char*)d_ws;

  prep_kernel<<<25, 256, 0, stream>>>(W1, b1, W2, b2, W3, b3, img);
  mlp_kernel<<<512, 512, 0, stream>>>(node, edge, img, (float*)d_out);
}

// Round 9
// 61.464 us; speedup vs baseline: 3.2759x; 1.6847x over previous
//
#include <hip/hip_runtime.h>
#include <stdint.h>
#include <stddef.h>

typedef __bf16 bf16;
typedef __attribute__((ext_vector_type(8))) __bf16 bf16x8;
typedef __attribute__((ext_vector_type(4))) __bf16 bf16x4;
typedef __attribute__((ext_vector_type(4))) float  f32x4;

// ---------------- geometry ----------------
// B = 262144. node: (B,19,4) f32, edge: (B,36,4) f32.
// compact first-4 nonzero rows of each -> x[32]; L1 32->256 relu; L2 256->128 relu;
// L3 128->34; log_softmax. Output (B,34) f32.
//
// Weight image (bf16 fragment-linear, built by prep_kernel in d_ws):
//   frag = 1024B: lane l holds 16B = W[k0..k0+8)[n], n = nt*16+(l&15), k0 = kk*32+8*(l>>4).
#define W1OFF  0               // 16 frags
#define W2OFF  (16*1024)       // 64 frags
#define W3OFF  (80*1024)       // 12 frags (N padded 34->48)
#define BOFF   (92*1024)       // b1[256] f32, b2[128], b3[48] = 1728B
#define IMGSZ  (92*1024 + 1728)
#define NCHUNK (IMGSZ/16)      // 5996 16B chunks
#define PERW   2048            // per-wave: x tile 1KB + stage 1KB
#define NWAVE  16
#define LDSSZ  (IMGSZ + NWAVE*PERW)   // 128704 B -> 1 block/CU, 16 waves (4/SIMD)

// swizzle for [16 rows][64B] bf16 tiles: XOR 16B-chunk index with (row>>1)&3
#define SWZ(s) ((((s)>>1)&3)<<4)

__global__ void prep_kernel(const float* __restrict__ W1, const float* __restrict__ b1,
                            const float* __restrict__ W2, const float* __restrict__ b2,
                            const float* __restrict__ W3, const float* __restrict__ b3,
                            char* __restrict__ img)
{
  int tid = blockIdx.x * 256 + threadIdx.x;
  if (tid < 92 * 64) {                       // 5888 weight chunks
    int fid = tid >> 6, l = tid & 63;
    int m = l & 15, gg = l >> 4;
    const float* W; int stride, n, k0;
    if (fid < 16)      { W = W1; stride = 256; n = fid * 16 + m;            k0 = gg * 8; }
    else if (fid < 80) { int f = fid - 16; W = W2; stride = 128; n = (f >> 3) * 16 + m; k0 = (f & 7) * 32 + gg * 8; }
    else               { int f = fid - 80; W = W3; stride = 34;  n = (f >> 2) * 16 + m; k0 = (f & 3) * 32 + gg * 8; }
    bf16x8 v;
    #pragma unroll
    for (int j = 0; j < 8; ++j) {
      float x = (stride == 34 && n >= 34) ? 0.f : W[(size_t)(k0 + j) * stride + n];
      v[j] = (bf16)x;
    }
    *(bf16x8*)(img + (size_t)tid * 16) = v;
  } else if (tid < 92 * 64 + 432) {          // biases, flat f32
    int i = tid - 92 * 64;
    float v;
    if (i < 256)      v = b1[i];
    else if (i < 384) v = b2[i - 256];
    else              { int j = i - 384; v = (j < 34) ? b3[j] : 0.f; }
    ((float*)(img + BOFF))[i] = v;
  }
}

// 1024-thread blocks hard-clamp the VGPR budget to 64 on this toolchain
// (R2/R3/R4, regardless of annotation). That killed R2 at demand ~108, but
// the rolled-kk structure measures 68 VGPR (R8) incl. 16 regs of in-flight
// global W2 frags -- removed here (W2 from LDS). Bet: demand <= 64 -> clean
// codegen + 16 waves/CU with all weights in LDS. Tell: WRITE_SIZE ~ 35MB.
__global__ __launch_bounds__(1024, 1) void mlp_kernel(
    const float* __restrict__ node, const float* __restrict__ edge,
    const char* __restrict__ img, float* __restrict__ out)
{
  __shared__ __align__(16) char sm[LDSSZ];
  const int tid  = threadIdx.x;
  const int lane = tid & 63;
  const int w    = tid >> 6;                 // 0..15
  const int blk  = blockIdx.x;

  // stage full weight image to LDS (coalesced 16B copies), one barrier total
  for (int c = tid; c < NCHUNK; c += 1024)
    *(f32x4*)(sm + (size_t)c * 16) = *(const f32x4*)(img + (size_t)c * 16);
  __syncthreads();

  char* const xw  = sm + IMGSZ + w * PERW;   // x tile (1KB, wave-private)
  char* const stg = xw + 1024;               // inter-layer stage (1KB)
  const float* const b1p = (const float*)(sm + BOFF);
  const float* const b2p = b1p + 256;
  const float* const b3p = b1p + 384;

  const int g   = lane >> 4;   // mfma 16-lane group
  const int m16 = lane & 15;   // sample col (compute) / weight row
  const int cl  = lane & 3;    // compaction lane within sample
  const int sl  = lane >> 2;   // compaction sample-in-tile (0..15)

  const float4* const np = (const float4*)node;   // 19 float4 per sample
  const float4* const ep = (const float4*)edge;   // 36 float4 per sample
  const f32x4 zf = {0.f, 0.f, 0.f, 0.f};

  #pragma unroll 1
  for (int p = 0; p < 4; ++p) {
    const int S = blk * 1024 + p * 256 + w * 16;

    // ---- load raw rows, compact into xw (no cross-pass prefetch) ----
    {
      const int s = S + sl;
      float4 nf[5], ef[9];
      #pragma unroll
      for (int i = 0; i < 5; ++i) {
        const int r = cl + 4 * i;
        nf[i] = (r < 19) ? np[(size_t)s * 19 + r] : make_float4(0.f, 0.f, 0.f, 0.f);
      }
      #pragma unroll
      for (int i = 0; i < 9; ++i)
        ef[i] = ep[(size_t)s * 36 + cl + 4 * i];

      uint32_t nm = 0; unsigned long long em = 0;
      #pragma unroll
      for (int i = 0; i < 5; ++i) {
        const int r = cl + 4 * i;
        if (r < 19 && (nf[i].x != 0.f || nf[i].y != 0.f || nf[i].z != 0.f || nf[i].w != 0.f))
          nm |= (1u << r);
      }
      #pragma unroll
      for (int i = 0; i < 9; ++i) {
        const int r = cl + 4 * i;
        if (ef[i].x != 0.f || ef[i].y != 0.f || ef[i].z != 0.f || ef[i].w != 0.f)
          em |= (1ull << r);
      }
      nm |= __shfl_xor(nm, 1); nm |= __shfl_xor(nm, 2);
      em |= __shfl_xor(em, 1); em |= __shfl_xor(em, 2);
      // zero-init my two 8B slots of the row (8 slots covered by 4 lanes);
      // wave-lockstep: zeros land before data writes below.
      bf16x4 zb; zb[0] = (bf16)0.f; zb[1] = (bf16)0.f; zb[2] = (bf16)0.f; zb[3] = (bf16)0.f;
      *(bf16x4*)(xw + sl * 64 + ((8 * cl)      ^ SWZ(sl))) = zb;
      *(bf16x4*)(xw + sl * 64 + ((8 * cl + 32) ^ SWZ(sl))) = zb;
      #pragma unroll
      for (int i = 0; i < 5; ++i) {
        const int r = cl + 4 * i;
        if (r < 19 && ((nm >> r) & 1u)) {
          const int slot = __popc(nm & ((1u << r) - 1u));
          if (slot < 4) {
            bf16x4 pk; pk[0] = (bf16)nf[i].x; pk[1] = (bf16)nf[i].y; pk[2] = (bf16)nf[i].z; pk[3] = (bf16)nf[i].w;
            *(bf16x4*)(xw + sl * 64 + ((8 * slot) ^ SWZ(sl))) = pk;
          }
        }
      }
      #pragma unroll
      for (int i = 0; i < 9; ++i) {
        const int r = cl + 4 * i;
        if ((em >> r) & 1ull) {
          const int slot = __popcll(em & ((1ull << r) - 1ull));
          if (slot < 4) {
            bf16x4 pk; pk[0] = (bf16)ef[i].x; pk[1] = (bf16)ef[i].y; pk[2] = (bf16)ef[i].z; pk[3] = (bf16)ef[i].w;
            *(bf16x4*)(xw + sl * 64 + ((32 + 8 * slot) ^ SWZ(sl))) = pk;
          }
        }
      }
    }

    // x B-fragment: lane holds x[s=m16][8g .. 8g+8)
    bf16x8 xf = *(const bf16x8*)(xw + m16 * 64 + ((16 * g) ^ SWZ(m16)));

    // ---- L1 (32->256) fused into L2 (256->128) per 32-feature chunk ----
    f32x4 acc2[8];
    #pragma unroll
    for (int i = 0; i < 8; ++i) acc2[i] = zf;

    #pragma unroll 1
    for (int kk = 0; kk < 8; ++kk) {
      __builtin_amdgcn_sched_barrier(0);     // keep live ranges tight per iter
      #pragma unroll
      for (int t = 0; t < 2; ++t) {
        const int nt1 = kk * 2 + t;
        bf16x8 wf = *(const bf16x8*)(sm + W1OFF + nt1 * 1024 + lane * 16);
        f32x4 d = __builtin_amdgcn_mfma_f32_16x16x32_bf16(wf, xf, zf, 0, 0, 0);
        f32x4 b = *(const f32x4*)(b1p + nt1 * 16 + 4 * g);
        bf16x4 pk;
        #pragma unroll
        for (int r = 0; r < 4; ++r) pk[r] = (bf16)fmaxf(d[r] + b[r], 0.f);
        // D is [feature][sample]: lane has 4 consecutive features of sample m16
        *(bf16x4*)(stg + m16 * 64 + ((32 * t + 8 * g) ^ SWZ(m16))) = pk;
      }
      bf16x8 sf = *(const bf16x8*)(stg + m16 * 64 + ((16 * g) ^ SWZ(m16)));
      #pragma unroll
      for (int nt2 = 0; nt2 < 8; ++nt2) {
        bf16x8 wf = *(const bf16x8*)(sm + W2OFF + (nt2 * 8 + kk) * 1024 + lane * 16);
        acc2[nt2] = __builtin_amdgcn_mfma_f32_16x16x32_bf16(wf, sf, acc2[nt2], 0, 0, 0);
      }
    }

    // ---- L2 out -> L3 (128->48 padded) ----
    f32x4 acc3[3];
    #pragma unroll
    for (int i = 0; i < 3; ++i) acc3[i] = zf;

    #pragma unroll
    for (int k2 = 0; k2 < 4; ++k2) {
      #pragma unroll
      for (int t = 0; t < 2; ++t) {
        const int nt2 = k2 * 2 + t;
        f32x4 b = *(const f32x4*)(b2p + nt2 * 16 + 4 * g);
        bf16x4 pk;
        #pragma unroll
        for (int r = 0; r < 4; ++r) pk[r] = (bf16)fmaxf(acc2[nt2][r] + b[r], 0.f);
        *(bf16x4*)(stg + m16 * 64 + ((32 * t + 8 * g) ^ SWZ(m16))) = pk;
      }
      bf16x8 sf = *(const bf16x8*)(stg + m16 * 64 + ((16 * g) ^ SWZ(m16)));
      #pragma unroll
      for (int nt3 = 0; nt3 < 3; ++nt3) {
        bf16x8 wf = *(const bf16x8*)(sm + W3OFF + (nt3 * 4 + k2) * 1024 + lane * 16);
        acc3[nt3] = __builtin_amdgcn_mfma_f32_16x16x32_bf16(wf, sf, acc3[nt3], 0, 0, 0);
      }
    }

    // ---- log_softmax over 34 classes (features spread over 4 lane-groups) ----
    float z[12];
    #pragma unroll
    for (int nt3 = 0; nt3 < 3; ++nt3) {
      f32x4 b = *(const f32x4*)(b3p + nt3 * 16 + 4 * g);
      #pragma unroll
      for (int r = 0; r < 4; ++r) {
        const int f = nt3 * 16 + 4 * g + r;
        z[nt3 * 4 + r] = (f < 34) ? (acc3[nt3][r] + b[r]) : -1e30f;
      }
    }
    float mx = z[0];
    #pragma unroll
    for (int i = 1; i < 12; ++i) mx = fmaxf(mx, z[i]);
    mx = fmaxf(mx, __shfl_xor(mx, 16));
    mx = fmaxf(mx, __shfl_xor(mx, 32));
    float sum = 0.f;
    #pragma unroll
    for (int i = 0; i < 12; ++i) sum += __expf(z[i] - mx);
    sum += __shfl_xor(sum, 16);
    sum += __shfl_xor(sum, 32);
    const float lse = mx + __logf(sum);

    float* orow = out + (size_t)(S + m16) * 34;
    *(float2*)(orow +  0 + 4 * g) = make_float2(z[0] - lse, z[1] - lse);
    *(float2*)(orow +  2 + 4 * g) = make_float2(z[2] - lse, z[3] - lse);
    *(float2*)(orow + 16 + 4 * g) = make_float2(z[4] - lse, z[5] - lse);
    *(float2*)(orow + 18 + 4 * g) = make_float2(z[6] - lse, z[7] - lse);
    if (g == 0)
      *(float2*)(orow + 32) = make_float2(z[8] - lse, z[9] - lse);
  }
}

extern "C" void kernel_launch(void* const* d_in, const int* in_sizes, int n_in,
                              void* d_out, int out_size, void* d_ws, size_t ws_size,
                              hipStream_t stream)
{
  const float* node = (const float*)d_in[0];
  const float* edge = (const float*)d_in[1];
  const float* W1   = (const float*)d_in[2];
  const float* b1   = (const float*)d_in[3];
  const float* W2   = (const float*)d_in[4];
  const float* b2   = (const float*)d_in[5];
  const float* W3   = (const float*)d_in[6];
  const float* b3   = (const float*)d_in[7];
  char* img = (char*)d_ws;

  prep_kernel<<<25, 256, 0, stream>>>(W1, b1, W2, b2, W3, b3, img);
  mlp_kernel<<<256, 1024, 0, stream>>>(node, edge, img, (float*)d_out);
}